// Round 2
// baseline (405.133 us; speedup 1.0000x reference)
//
#include <hip/hip_runtime.h>

// VectorQuantizer via bf16 hi/lo MFMA GEMM.
// R9: 128x256 block tile (code tile doubled -> A restaged 4x not 8x),
// 512 threads / 8 waves, single 96KB-dbuf barrier domain (512 MFMA/phase),
// 2-deep prefetch with counted vmcnt(6), involution bank-swizzle, setprio,
// 4 candidate columns x top-2 -> 8-way exact f32 rescore,
// prepw+convx fused into one launch.
// x[65536,256] f32, W[1024,256] f32.
// Out (f32, concat): quantized[16777216] | loss[1] | idx[65536].
// Xhat (bf16 [hi|lo] per row, 64 MB) lives in d_out until each block overwrites
// its own rows with quantized in the epilogue (disjoint row ranges per block).

#define NROWS    65536
#define DDIM     256
#define KCODES   1024
#define DEXT     512        // [hi(256) | lo(256)] bf16
#define ND_TOTAL 16777216

typedef __attribute__((ext_vector_type(8))) short bf16x8;
typedef __attribute__((ext_vector_type(4))) float floatx4;

__device__ __forceinline__ unsigned short f2bf(float f) {
    unsigned int u = __float_as_uint(f);
    return (unsigned short)((u + 0x7FFFu + ((u >> 16) & 1u)) >> 16);
}
__device__ __forceinline__ float bf2f(unsigned short h) {
    return __uint_as_float((unsigned int)h << 16);
}
__device__ __forceinline__ void split4(float4 v, ushort4* hi, ushort4* lo) {
    unsigned short hx = f2bf(v.x), hy = f2bf(v.y), hz = f2bf(v.z), hw = f2bf(v.w);
    *hi = make_ushort4(hx, hy, hz, hw);
    *lo = make_ushort4(f2bf(v.x - bf2f(hx)), f2bf(v.y - bf2f(hy)),
                       f2bf(v.z - bf2f(hz)), f2bf(v.w - bf2f(hw)));
}
__device__ __forceinline__ void async_copy16(void* lds, const void* g) {
    __builtin_amdgcn_global_load_lds(
        (const __attribute__((address_space(1))) unsigned int*)g,
        (__attribute__((address_space(3))) unsigned int*)lds, 16, 0, 0);
}

// merge top-2 (v1,k1,v2,k2) with (o1,ok1,o2,ok2); lowest-k on ties
__device__ __forceinline__ void merge2(float& v1, int& k1, float& v2, int& k2,
                                       float o1, int ok1, float o2, int ok2) {
    bool aw = (v1 < o1) || (v1 == o1 && k1 < ok1);
    float ca = aw ? v2 : v1; int kca = aw ? k2 : k1;
    float cb = aw ? o1 : o2; int kcb = aw ? ok1 : ok2;
    float nv1 = aw ? v1 : o1; int nk1 = aw ? k1 : ok1;
    bool cw = (ca < cb) || (ca == cb && kca < kcb);
    v1 = nv1; k1 = nk1;
    v2 = cw ? ca : cb; k2 = cw ? kca : kcb;
}

// Fused prep: blocks [0,16384) convert x -> Xhat; blocks [16384,16388) build
// What/w2/w2m and zero the loss accumulator.
__global__ __launch_bounds__(256) void vq_prep(
    const float* __restrict__ x, unsigned short* __restrict__ Xhat,
    const float* __restrict__ W, unsigned short* __restrict__ What,
    float* __restrict__ w2, float* __restrict__ w2m, float* __restrict__ lossws)
{
    const int b = blockIdx.x;
    if (b < 16384) {
        int gid = b * 256 + threadIdx.x;
        int row = gid >> 6, q = gid & 63;
        float4 v = ((const float4*)x)[gid];
        ushort4 hv, lv;
        split4(v, &hv, &lv);
        unsigned short* r = Xhat + (size_t)row * DEXT;
        *(ushort4*)(r + q * 4) = hv;
        *(ushort4*)(r + 256 + q * 4) = lv;
    } else {
        int k = (b - 16384) * 256 + threadIdx.x;
        if (k == 0) lossws[0] = 0.0f;
        const float4* wr = (const float4*)(W + (size_t)k * DDIM);
        unsigned short* hrow = What + (size_t)k * DEXT;
        float s = 0.0f;
        for (int i = 0; i < 64; ++i) {
            float4 v = wr[i];
            s = fmaf(v.x, v.x, s); s = fmaf(v.y, v.y, s);
            s = fmaf(v.z, v.z, s); s = fmaf(v.w, v.w, s);
            ushort4 hv, lv;
            split4(v, &hv, &lv);
            *(ushort4*)(hrow + i * 4) = hv;
            *(ushort4*)(hrow + 256 + i * 4) = lv;
        }
        w2[k] = s;
        w2m[k] = s - 256.0f;
    }
}

__global__ __launch_bounds__(512, 2) void vq_main(
    const unsigned short* Xhat, const unsigned short* __restrict__ What,
    const float* __restrict__ x, const float* __restrict__ W,
    const float* __restrict__ w2, const float* __restrict__ w2m,
    float* qout, float* lossws, float* idx_out)
{
    // 96 KB: [buf 0|1][A_hi 8K | A_lo 8K | B_hi 16K | B_lo 16K] (ushort counts:
    // A_hi [128][32] @0, A_lo @4096, B_hi [256][32] @8192, B_lo @16384; stride 24576)
    __shared__ __align__(16) unsigned short smem[2 * 24576];
    __shared__ float Wm[KCODES];              // 4 KB staged w2m

    // epilogue arrays aliased onto smem buf0 (staging dead after the q-loop)
    int*   rk1   = (int*)smem;                // [4][128]
    int*   rk2   = rk1 + 512;                 // [4][128]
    int*   candk = rk2 + 512;                 // [128][8]
    float* resc  = (float*)(candk + 1024);    // [128][8]
    int*   fink  = (int*)(resc + 1024);       // [128]

    const int tid  = threadIdx.x;
    const int wave = tid >> 6, lane = tid & 63;
    const int quad = lane >> 4, l15 = lane & 15;
    const int wr = wave >> 2, wc = wave & 3;  // 2 row-strips x 4 code-strips
    const int row0 = blockIdx.x * 128;

    // stage w2m (first use is after many barriers)
    Wm[tid] = w2m[tid];
    Wm[512 + tid] = w2m[512 + tid];

    // in-lane packed top-2: low 4 mantissa bits = payload (j<<2)|ct, err <= 15 ulp
    float s1[16], s2[16];
    #pragma unroll
    for (int s = 0; s < 16; ++s) { s1[s] = 3.0e38f; s2[s] = 3.0e38f; }

    // staging geometry: thread -> (row r0, part p0); source part swizzled by the
    // involution p ^= (r>>1)&3 so the LINEAR global_load_lds dest yields a
    // bank-conflict-free read layout (read applies the same XOR).
    const int r0 = tid >> 2, p0 = tid & 3;
    const int psw = (p0 ^ ((r0 >> 1) & 3)) << 3;        // ushort offset in row chunk
    const int quadS8 = (quad ^ ((l15 >> 1) & 3)) << 3;  // read-side swizzled part
    const unsigned short* Ab = Xhat + (size_t)row0 * DEXT;

    auto STAGE = [&](int q, int cb) {
        const int ct = q >> 3, dc = (q & 7) << 5;
        const unsigned short* An = Ab + (size_t)r0 * DEXT + dc + psw;
        const unsigned short* Bn = What + ((size_t)(ct * 256 + r0)) * DEXT + dc + psw;
        unsigned short* L = smem + cb * 24576 + tid * 8;
        async_copy16(L,          An);                      // A_hi rows 0-127
        async_copy16(L + 4096,   An + 256);                // A_lo
        async_copy16(L + 8192,   Bn);                      // B_hi rows 0-127
        async_copy16(L + 12288,  Bn + 128 * DEXT);         // B_hi rows 128-255
        async_copy16(L + 16384,  Bn + 256);                // B_lo rows 0-127
        async_copy16(L + 20480,  Bn + 128 * DEXT + 256);   // B_lo rows 128-255
    };

    STAGE(0, 0);
    STAGE(1, 1);

    floatx4 acc[4][4];
    #pragma unroll
    for (int i = 0; i < 4; ++i)
        #pragma unroll
        for (int j = 0; j < 4; ++j) acc[i][j] = (floatx4){0.f, 0.f, 0.f, 0.f};

    // 32 phases: q = ct*8 + h, dc = h*32. Per phase: 6 staged tiles, 64 MFMAs/wave
    // (all 4 hi/lo cross products -> exact f32-accumulated S).
    #pragma unroll 1
    for (int q = 0; q < 32; ++q) {
        const int cb = q & 1;
        if (q != 31) { asm volatile("s_waitcnt vmcnt(6)" ::: "memory"); }
        else         { asm volatile("s_waitcnt vmcnt(0)" ::: "memory"); }
        __builtin_amdgcn_s_barrier();              // buf cb staged for all waves
        asm volatile("" ::: "memory");
        __builtin_amdgcn_s_setprio(1);

        const unsigned short* Sb = smem + cb * 24576;
        bf16x8 a0[4], a1[4], b0[4], b1[4];
        #pragma unroll
        for (int i = 0; i < 4; ++i) {
            const int ro = (wr * 64 + i * 16 + l15) * 32 + quadS8;
            a0[i] = *(const bf16x8*)(Sb + ro);
            a1[i] = *(const bf16x8*)(Sb + 4096 + ro);
        }
        #pragma unroll
        for (int j = 0; j < 4; ++j) {
            const int ro = (wc * 64 + j * 16 + l15) * 32 + quadS8;
            b0[j] = *(const bf16x8*)(Sb + 8192 + ro);
            b1[j] = *(const bf16x8*)(Sb + 16384 + ro);
        }
        #pragma unroll
        for (int i = 0; i < 4; ++i)
            #pragma unroll
            for (int j = 0; j < 4; ++j) {
                acc[i][j] = __builtin_amdgcn_mfma_f32_16x16x32_bf16(a0[i], b0[j], acc[i][j], 0, 0, 0);
                acc[i][j] = __builtin_amdgcn_mfma_f32_16x16x32_bf16(a1[i], b1[j], acc[i][j], 0, 0, 0);
                acc[i][j] = __builtin_amdgcn_mfma_f32_16x16x32_bf16(a0[i], b1[j], acc[i][j], 0, 0, 0);
                acc[i][j] = __builtin_amdgcn_mfma_f32_16x16x32_bf16(a1[i], b0[j], acc[i][j], 0, 0, 0);
            }
        __builtin_amdgcn_s_setprio(0);
        asm volatile("s_waitcnt lgkmcnt(0)" ::: "memory");  // all buf-cb reads done
        __builtin_amdgcn_s_barrier();                       // ... for every wave
        asm volatile("" ::: "memory");
        if (q + 2 < 32) STAGE(q + 2, cb);                   // overwrite buf cb

        if ((q & 7) == 7) {
            // fold: v = (w2-256) - 2*S, payload = (j<<2)|ct in low 4 bits
            const int ctf = q >> 3;
            #pragma unroll
            for (int j = 0; j < 4; ++j) {
                int cc = ctf * 256 + wc * 64 + j * 16 + l15;
                float wm = Wm[cc];
                unsigned pay = (unsigned)((j << 2) | ctf);
                #pragma unroll
                for (int i = 0; i < 4; ++i)
                    #pragma unroll
                    for (int r = 0; r < 4; ++r) {
                        float v = fmaf(-2.0f, acc[i][j][r], wm);
                        float pf = __uint_as_float((__float_as_uint(v) & 0xFFFFFFF0u) | pay);
                        int s = i * 4 + r;
                        float t = fminf(s1[s], pf);
                        s2[s] = fminf(s2[s], fmaxf(s1[s], pf));
                        s1[s] = t;
                    }
            }
            #pragma unroll
            for (int i = 0; i < 4; ++i)
                #pragma unroll
                for (int j = 0; j < 4; ++j) acc[i][j] = (floatx4){0.f, 0.f, 0.f, 0.f};
        }
    }

    // decode packed top-2 -> explicit (val, code)
    float v1[16], v2[16];
    int k1[16], k2[16];
    #pragma unroll
    for (int s = 0; s < 16; ++s) {
        unsigned u1 = __float_as_uint(s1[s]) & 15u;
        unsigned u2 = __float_as_uint(s2[s]) & 15u;
        v1[s] = s1[s]; v2[s] = s2[s];
        k1[s] = (int)(u1 & 3u) * 256 + wc * 64 + (int)(u1 >> 2) * 16 + l15;
        k2[s] = (int)(u2 & 3u) * 256 + wc * 64 + (int)(u2 >> 2) * 16 + l15;
    }
    // cross-lane merge across the 16 l15 lanes (explicit val+idx)
    #pragma unroll
    for (int m = 1; m < 16; m <<= 1) {
        #pragma unroll
        for (int s = 0; s < 16; ++s) {
            float o1 = __shfl_xor(v1[s], m, 64);
            int  ok1 = __shfl_xor(k1[s], m, 64);
            float o2 = __shfl_xor(v2[s], m, 64);
            int  ok2 = __shfl_xor(k2[s], m, 64);
            merge2(v1[s], k1[s], v2[s], k2[s], o1, ok1, o2, ok2);
        }
    }
    if (l15 == 0) {   // publish per-column top-2 for all 16 row-slots
        #pragma unroll
        for (int s = 0; s < 16; ++s) {
            int row = wr * 64 + (s >> 2) * 16 + quad * 4 + (s & 3);
            rk1[wc * 128 + row] = k1[s];
            rk2[wc * 128 + row] = k2[s];
        }
    }
    __syncthreads();
    if (tid < 128) {   // 8 candidates per row: top-2 from each disjoint code column
        #pragma unroll
        for (int h = 0; h < 4; ++h) {
            candk[tid * 8 + h * 2 + 0] = rk1[h * 128 + tid];
            candk[tid * 8 + h * 2 + 1] = rk2[h * 128 + tid];
        }
    }
    __syncthreads();
    // exact f32 rescore of all 8 candidates (1024 jobs, 2 per thread)
    #pragma unroll
    for (int j2 = 0; j2 < 2; ++j2) {
        int job = tid + j2 * 512;
        int r = job >> 3, cn = job & 7;
        int k = candk[r * 8 + cn];
        const float4* xr  = (const float4*)(x + (size_t)(row0 + r) * DDIM);
        const float4* wrp = (const float4*)(W + (size_t)k * DDIM);
        float dot = 0.0f;
        #pragma unroll 8
        for (int i = 0; i < 64; ++i) {
            float4 va = xr[i], vb = wrp[i];
            dot = fmaf(va.x, vb.x, dot); dot = fmaf(va.y, vb.y, dot);
            dot = fmaf(va.z, vb.z, dot); dot = fmaf(va.w, vb.w, dot);
        }
        resc[r * 8 + cn] = fmaf(-2.0f, dot, w2[k]);
    }
    __syncthreads();
    if (tid < 128) {
        float bd = resc[tid * 8 + 0];
        int   bk = candk[tid * 8 + 0];
        #pragma unroll
        for (int cn = 1; cn < 8; ++cn) {
            float d = resc[tid * 8 + cn];
            int   k = candk[tid * 8 + cn];
            if (d < bd || (d == bd && k < bk)) { bd = d; bk = k; }
        }
        fink[tid] = bk;
        idx_out[row0 + tid] = (float)bk;
    }
    __syncthreads();

    // epilogue: gather W[idx] -> quantized (overwrites this block's Xhat rows), loss
    const int c4 = tid & 63, rsub = tid >> 6;   // rsub 0..7
    float lsum = 0.0f;
    for (int it2 = 0; it2 < 16; ++it2) {
        int r = it2 * 8 + rsub;
        int k = fink[r];
        float4 wv = ((const float4*)(W + (size_t)k * DDIM))[c4];
        float4 xv = ((const float4*)(x + (size_t)(row0 + r) * DDIM))[c4];
        ((float4*)(qout + (size_t)(row0 + r) * DDIM))[c4] = wv;
        float dx = wv.x - xv.x, dy = wv.y - xv.y;
        float dz = wv.z - xv.z, dw = wv.w - xv.w;
        lsum = fmaf(dx, dx, lsum); lsum = fmaf(dy, dy, lsum);
        lsum = fmaf(dz, dz, lsum); lsum = fmaf(dw, dw, lsum);
    }
    #pragma unroll
    for (int off = 32; off > 0; off >>= 1) lsum += __shfl_down(lsum, off, 64);
    if (lane == 0) atomicAdd(lossws, lsum);
}

__global__ void vq_fin(const float* __restrict__ lossws, float* __restrict__ loss_out) {
    loss_out[0] = 1.25f * lossws[0] / (float)ND_TOTAL;
}

extern "C" void kernel_launch(void* const* d_in, const int* in_sizes, int n_in,
                              void* d_out, int out_size, void* d_ws, size_t ws_size,
                              hipStream_t stream) {
    const float* x = (const float*)d_in[0];
    const float* W = (const float*)d_in[1];
    float* out = (float*)d_out;
    unsigned short* Xhat = (unsigned short*)d_out;
    unsigned short* What = (unsigned short*)d_ws;
    float* w2     = (float*)((char*)d_ws + (1 << 20));
    float* w2m    = w2 + 1024;
    float* lossws = w2 + 2048;
    float* idx_out = out + (size_t)ND_TOTAL + 1;

    vq_prep<<<16388, 256, 0, stream>>>(x, Xhat, W, What, w2, w2m, lossws);
    vq_main<<<512, 512, 0, stream>>>(Xhat, What, x, W, w2, w2m, out, lossws, idx_out);
    vq_fin<<<1, 1, 0, stream>>>(lossws, out + ND_TOTAL);
}

// Round 3
// 400.105 us; speedup vs baseline: 1.0126x; 1.0126x over previous
//
#include <hip/hip_runtime.h>

// VectorQuantizer via bf16 hi/lo MFMA GEMM.
// R10: 128x256 tile, 8 waves, TRIPLE-buffered LDS (3x48KB) with 4-sub-phase
// interleave per K-phase: {barrier; ds_read cluster; 2 stage-issues; 16 MFMA}
// x4. No lgkm-drain barrier (stage target is never the read buffer). Counted
// vmcnt(6) once per phase. Involution bank-swizzle, setprio around MFMA.
// x[65536,256] f32, W[1024,256] f32.
// Out (f32, concat): quantized[16777216] | loss[1] | idx[65536].
// Xhat (bf16 [hi|lo] per row, 64 MB) lives in d_out until each block overwrites
// its own rows with quantized in the epilogue (disjoint row ranges per block).

#define NROWS    65536
#define DDIM     256
#define KCODES   1024
#define DEXT     512        // [hi(256) | lo(256)] bf16
#define ND_TOTAL 16777216

typedef __attribute__((ext_vector_type(8))) short bf16x8;
typedef __attribute__((ext_vector_type(4))) float floatx4;

__device__ __forceinline__ unsigned short f2bf(float f) {
    unsigned int u = __float_as_uint(f);
    return (unsigned short)((u + 0x7FFFu + ((u >> 16) & 1u)) >> 16);
}
__device__ __forceinline__ float bf2f(unsigned short h) {
    return __uint_as_float((unsigned int)h << 16);
}
__device__ __forceinline__ void split4(float4 v, ushort4* hi, ushort4* lo) {
    unsigned short hx = f2bf(v.x), hy = f2bf(v.y), hz = f2bf(v.z), hw = f2bf(v.w);
    *hi = make_ushort4(hx, hy, hz, hw);
    *lo = make_ushort4(f2bf(v.x - bf2f(hx)), f2bf(v.y - bf2f(hy)),
                       f2bf(v.z - bf2f(hz)), f2bf(v.w - bf2f(hw)));
}
__device__ __forceinline__ void async_copy16(void* lds, const void* g) {
    __builtin_amdgcn_global_load_lds(
        (const __attribute__((address_space(1))) unsigned int*)g,
        (__attribute__((address_space(3))) unsigned int*)lds, 16, 0, 0);
}

// merge top-2 (v1,k1,v2,k2) with (o1,ok1,o2,ok2); lowest-k on ties
__device__ __forceinline__ void merge2(float& v1, int& k1, float& v2, int& k2,
                                       float o1, int ok1, float o2, int ok2) {
    bool aw = (v1 < o1) || (v1 == o1 && k1 < ok1);
    float ca = aw ? v2 : v1; int kca = aw ? k2 : k1;
    float cb = aw ? o1 : o2; int kcb = aw ? ok1 : ok2;
    float nv1 = aw ? v1 : o1; int nk1 = aw ? k1 : ok1;
    bool cw = (ca < cb) || (ca == cb && kca < kcb);
    v1 = nv1; k1 = nk1;
    v2 = cw ? ca : cb; k2 = cw ? kca : kcb;
}

// Fused prep: blocks [0,16384) convert x -> Xhat; blocks [16384,16388) build
// What/w2/w2m and zero the loss accumulator.
__global__ __launch_bounds__(256) void vq_prep(
    const float* __restrict__ x, unsigned short* __restrict__ Xhat,
    const float* __restrict__ W, unsigned short* __restrict__ What,
    float* __restrict__ w2, float* __restrict__ w2m, float* __restrict__ lossws)
{
    const int b = blockIdx.x;
    if (b < 16384) {
        int gid = b * 256 + threadIdx.x;
        int row = gid >> 6, q = gid & 63;
        float4 v = ((const float4*)x)[gid];
        ushort4 hv, lv;
        split4(v, &hv, &lv);
        unsigned short* r = Xhat + (size_t)row * DEXT;
        *(ushort4*)(r + q * 4) = hv;
        *(ushort4*)(r + 256 + q * 4) = lv;
    } else {
        int k = (b - 16384) * 256 + threadIdx.x;
        if (k == 0) lossws[0] = 0.0f;
        const float4* wr = (const float4*)(W + (size_t)k * DDIM);
        unsigned short* hrow = What + (size_t)k * DEXT;
        float s = 0.0f;
        for (int i = 0; i < 64; ++i) {
            float4 v = wr[i];
            s = fmaf(v.x, v.x, s); s = fmaf(v.y, v.y, s);
            s = fmaf(v.z, v.z, s); s = fmaf(v.w, v.w, s);
            ushort4 hv, lv;
            split4(v, &hv, &lv);
            *(ushort4*)(hrow + i * 4) = hv;
            *(ushort4*)(hrow + 256 + i * 4) = lv;
        }
        w2[k] = s;
        w2m[k] = s - 256.0f;
    }
}

__global__ __launch_bounds__(512, 2) void vq_main(
    const unsigned short* Xhat, const unsigned short* __restrict__ What,
    const float* __restrict__ x, const float* __restrict__ W,
    const float* __restrict__ w2, const float* __restrict__ w2m,
    float* qout, float* lossws, float* idx_out)
{
    // 144 KB: 3 bufs x [A_hi 4096 | A_lo 4096 | B_hi 8192 | B_lo 8192] ushorts
    __shared__ __align__(16) unsigned short smem[3 * 24576];
    __shared__ float Wm[KCODES];              // 4 KB staged w2m

    // epilogue arrays aliased onto smem buf0 (staging dead after the q-loop;
    // buf0 last read in phase 30, all waves past phase-31 entry barrier before
    // any publish -> disjoint-in-time)
    int*   rk1   = (int*)smem;                // [4][128]
    int*   rk2   = rk1 + 512;                 // [4][128]
    int*   candk = rk2 + 512;                 // [128][8]
    float* resc  = (float*)(candk + 1024);    // [128][8]
    int*   fink  = (int*)(resc + 1024);       // [128]

    const int tid  = threadIdx.x;
    const int wave = tid >> 6, lane = tid & 63;
    const int quad = lane >> 4, l15 = lane & 15;
    const int wr = wave >> 2, wc = wave & 3;  // 2 row-strips x 4 code-strips
    const int row0 = blockIdx.x * 128;

    // stage w2m (first use is after many barriers)
    Wm[tid] = w2m[tid];
    Wm[512 + tid] = w2m[512 + tid];

    // in-lane packed top-2: low 4 mantissa bits = payload (j<<2)|ct, err <= 15 ulp
    float s1[16], s2[16];
    #pragma unroll
    for (int s = 0; s < 16; ++s) { s1[s] = 3.0e38f; s2[s] = 3.0e38f; }

    // staging geometry: thread -> (row r0, part p0); source part swizzled by the
    // involution p ^= (r>>1)&3 so the LINEAR global_load_lds dest yields a
    // bank-conflict-free read layout (read applies the same XOR).
    const int r0 = tid >> 2, p0 = tid & 3;
    const int psw = (p0 ^ ((r0 >> 1) & 3)) << 3;        // ushort offset in row chunk
    const int quadS8 = (quad ^ ((l15 >> 1) & 3)) << 3;  // read-side swizzled part
    const unsigned short* Ab = Xhat + (size_t)row0 * DEXT;

    // one third of a tile-stage (2 of 6 global_load_lds), part in {0,1,2}
    auto STAGEP = [&](int q, int part) {
        const int ct = q >> 3, dc = (q & 7) << 5;
        unsigned short* L = smem + (q % 3) * 24576 + tid * 8;
        if (part == 0) {
            const unsigned short* An = Ab + (size_t)r0 * DEXT + dc + psw;
            async_copy16(L,        An);                      // A_hi rows 0-127
            async_copy16(L + 4096, An + 256);                // A_lo
        } else if (part == 1) {
            const unsigned short* Bn = What + ((size_t)(ct * 256 + r0)) * DEXT + dc + psw;
            async_copy16(L + 8192,  Bn);                     // B_hi rows 0-127
            async_copy16(L + 12288, Bn + 128 * DEXT);        // B_hi rows 128-255
        } else {
            const unsigned short* Bn = What + ((size_t)(ct * 256 + r0)) * DEXT + dc + psw;
            async_copy16(L + 16384, Bn + 256);               // B_lo rows 0-127
            async_copy16(L + 20480, Bn + 128 * DEXT + 256);  // B_lo rows 128-255
        }
    };

    STAGEP(0, 0); STAGEP(0, 1); STAGEP(0, 2);
    STAGEP(1, 0); STAGEP(1, 1); STAGEP(1, 2);

    floatx4 acc[4][4];
    #pragma unroll
    for (int i = 0; i < 4; ++i)
        #pragma unroll
        for (int j = 0; j < 4; ++j) acc[i][j] = (floatx4){0.f, 0.f, 0.f, 0.f};

    // 32 phases (q = ct*8 + h, K-chunk dc = h*32), each split into 4 sub-phases
    // (one C-column quadrant j each: 16 MFMA = 4 i x 4 hi/lo cross products).
    // STAGE(q+2) targets buf (q+2)%3 which no wave reads in phases q or q+1.
    #pragma unroll 1
    for (int q = 0; q < 32; ++q) {
        const unsigned short* Sb = smem + (q % 3) * 24576;
        if (q != 31) { asm volatile("s_waitcnt vmcnt(6)" ::: "memory"); }
        else         { asm volatile("s_waitcnt vmcnt(0)" ::: "memory"); }

        bf16x8 a0[4], a1[4];
        // ---- sub-phase 0: a-cluster + b[0], no stage issue ----
        __builtin_amdgcn_s_barrier();
        asm volatile("" ::: "memory");
        #pragma unroll
        for (int i = 0; i < 4; ++i) {
            const int ro = (wr * 64 + i * 16 + l15) * 32 + quadS8;
            a0[i] = *(const bf16x8*)(Sb + ro);
            a1[i] = *(const bf16x8*)(Sb + 4096 + ro);
        }
        {
            const int ro = (wc * 64 + 0 * 16 + l15) * 32 + quadS8;
            bf16x8 b0 = *(const bf16x8*)(Sb + 8192 + ro);
            bf16x8 b1 = *(const bf16x8*)(Sb + 16384 + ro);
            __builtin_amdgcn_s_setprio(1);
            #pragma unroll
            for (int i = 0; i < 4; ++i) {
                acc[i][0] = __builtin_amdgcn_mfma_f32_16x16x32_bf16(a0[i], b0, acc[i][0], 0, 0, 0);
                acc[i][0] = __builtin_amdgcn_mfma_f32_16x16x32_bf16(a1[i], b1, acc[i][0], 0, 0, 0);
                acc[i][0] = __builtin_amdgcn_mfma_f32_16x16x32_bf16(a0[i], b1, acc[i][0], 0, 0, 0);
                acc[i][0] = __builtin_amdgcn_mfma_f32_16x16x32_bf16(a1[i], b0, acc[i][0], 0, 0, 0);
            }
            __builtin_amdgcn_s_setprio(0);
        }
        // ---- sub-phases 1..3: b[j] + one stage part each ----
        #pragma unroll
        for (int j = 1; j < 4; ++j) {
            __builtin_amdgcn_s_barrier();
            asm volatile("" ::: "memory");
            const int ro = (wc * 64 + j * 16 + l15) * 32 + quadS8;
            bf16x8 b0 = *(const bf16x8*)(Sb + 8192 + ro);
            bf16x8 b1 = *(const bf16x8*)(Sb + 16384 + ro);
            if (q + 2 < 32) STAGEP(q + 2, j - 1);
            __builtin_amdgcn_s_setprio(1);
            #pragma unroll
            for (int i = 0; i < 4; ++i) {
                acc[i][j] = __builtin_amdgcn_mfma_f32_16x16x32_bf16(a0[i], b0, acc[i][j], 0, 0, 0);
                acc[i][j] = __builtin_amdgcn_mfma_f32_16x16x32_bf16(a1[i], b1, acc[i][j], 0, 0, 0);
                acc[i][j] = __builtin_amdgcn_mfma_f32_16x16x32_bf16(a0[i], b1, acc[i][j], 0, 0, 0);
                acc[i][j] = __builtin_amdgcn_mfma_f32_16x16x32_bf16(a1[i], b0, acc[i][j], 0, 0, 0);
            }
            __builtin_amdgcn_s_setprio(0);
        }

        if ((q & 7) == 7) {
            // fold: v = (w2-256) - 2*S, payload = (j<<2)|ct in low 4 bits
            const int ctf = q >> 3;
            #pragma unroll
            for (int j = 0; j < 4; ++j) {
                int cc = ctf * 256 + wc * 64 + j * 16 + l15;
                float wm = Wm[cc];
                unsigned pay = (unsigned)((j << 2) | ctf);
                #pragma unroll
                for (int i = 0; i < 4; ++i)
                    #pragma unroll
                    for (int r = 0; r < 4; ++r) {
                        float v = fmaf(-2.0f, acc[i][j][r], wm);
                        float pf = __uint_as_float((__float_as_uint(v) & 0xFFFFFFF0u) | pay);
                        int s = i * 4 + r;
                        float t = fminf(s1[s], pf);
                        s2[s] = fminf(s2[s], fmaxf(s1[s], pf));
                        s1[s] = t;
                    }
            }
            #pragma unroll
            for (int i = 0; i < 4; ++i)
                #pragma unroll
                for (int j = 0; j < 4; ++j) acc[i][j] = (floatx4){0.f, 0.f, 0.f, 0.f};
        }
    }

    // decode packed top-2 -> explicit (val, code)
    float v1[16], v2[16];
    int k1[16], k2[16];
    #pragma unroll
    for (int s = 0; s < 16; ++s) {
        unsigned u1 = __float_as_uint(s1[s]) & 15u;
        unsigned u2 = __float_as_uint(s2[s]) & 15u;
        v1[s] = s1[s]; v2[s] = s2[s];
        k1[s] = (int)(u1 & 3u) * 256 + wc * 64 + (int)(u1 >> 2) * 16 + l15;
        k2[s] = (int)(u2 & 3u) * 256 + wc * 64 + (int)(u2 >> 2) * 16 + l15;
    }
    // cross-lane merge across the 16 l15 lanes (explicit val+idx)
    #pragma unroll
    for (int m = 1; m < 16; m <<= 1) {
        #pragma unroll
        for (int s = 0; s < 16; ++s) {
            float o1 = __shfl_xor(v1[s], m, 64);
            int  ok1 = __shfl_xor(k1[s], m, 64);
            float o2 = __shfl_xor(v2[s], m, 64);
            int  ok2 = __shfl_xor(k2[s], m, 64);
            merge2(v1[s], k1[s], v2[s], k2[s], o1, ok1, o2, ok2);
        }
    }
    if (l15 == 0) {   // publish per-column top-2 for all 16 row-slots
        #pragma unroll
        for (int s = 0; s < 16; ++s) {
            int row = wr * 64 + (s >> 2) * 16 + quad * 4 + (s & 3);
            rk1[wc * 128 + row] = k1[s];
            rk2[wc * 128 + row] = k2[s];
        }
    }
    __syncthreads();
    if (tid < 128) {   // 8 candidates per row: top-2 from each disjoint code column
        #pragma unroll
        for (int h = 0; h < 4; ++h) {
            candk[tid * 8 + h * 2 + 0] = rk1[h * 128 + tid];
            candk[tid * 8 + h * 2 + 1] = rk2[h * 128 + tid];
        }
    }
    __syncthreads();
    // exact f32 rescore of all 8 candidates (1024 jobs, 2 per thread)
    #pragma unroll
    for (int j2 = 0; j2 < 2; ++j2) {
        int job = tid + j2 * 512;
        int r = job >> 3, cn = job & 7;
        int k = candk[r * 8 + cn];
        const float4* xr  = (const float4*)(x + (size_t)(row0 + r) * DDIM);
        const float4* wrp = (const float4*)(W + (size_t)k * DDIM);
        float dot = 0.0f;
        #pragma unroll 8
        for (int i = 0; i < 64; ++i) {
            float4 va = xr[i], vb = wrp[i];
            dot = fmaf(va.x, vb.x, dot); dot = fmaf(va.y, vb.y, dot);
            dot = fmaf(va.z, vb.z, dot); dot = fmaf(va.w, vb.w, dot);
        }
        resc[r * 8 + cn] = fmaf(-2.0f, dot, w2[k]);
    }
    __syncthreads();
    if (tid < 128) {
        float bd = resc[tid * 8 + 0];
        int   bk = candk[tid * 8 + 0];
        #pragma unroll
        for (int cn = 1; cn < 8; ++cn) {
            float d = resc[tid * 8 + cn];
            int   k = candk[tid * 8 + cn];
            if (d < bd || (d == bd && k < bk)) { bd = d; bk = k; }
        }
        fink[tid] = bk;
        idx_out[row0 + tid] = (float)bk;
    }
    __syncthreads();

    // epilogue: gather W[idx] -> quantized (overwrites this block's Xhat rows), loss
    const int c4 = tid & 63, rsub = tid >> 6;   // rsub 0..7
    float lsum = 0.0f;
    for (int it2 = 0; it2 < 16; ++it2) {
        int r = it2 * 8 + rsub;
        int k = fink[r];
        float4 wv = ((const float4*)(W + (size_t)k * DDIM))[c4];
        float4 xv = ((const float4*)(x + (size_t)(row0 + r) * DDIM))[c4];
        ((float4*)(qout + (size_t)(row0 + r) * DDIM))[c4] = wv;
        float dx = wv.x - xv.x, dy = wv.y - xv.y;
        float dz = wv.z - xv.z, dw = wv.w - xv.w;
        lsum = fmaf(dx, dx, lsum); lsum = fmaf(dy, dy, lsum);
        lsum = fmaf(dz, dz, lsum); lsum = fmaf(dw, dw, lsum);
    }
    #pragma unroll
    for (int off = 32; off > 0; off >>= 1) lsum += __shfl_down(lsum, off, 64);
    if (lane == 0) atomicAdd(lossws, lsum);
}

__global__ void vq_fin(const float* __restrict__ lossws, float* __restrict__ loss_out) {
    loss_out[0] = 1.25f * lossws[0] / (float)ND_TOTAL;
}

extern "C" void kernel_launch(void* const* d_in, const int* in_sizes, int n_in,
                              void* d_out, int out_size, void* d_ws, size_t ws_size,
                              hipStream_t stream) {
    const float* x = (const float*)d_in[0];
    const float* W = (const float*)d_in[1];
    float* out = (float*)d_out;
    unsigned short* Xhat = (unsigned short*)d_out;
    unsigned short* What = (unsigned short*)d_ws;
    float* w2     = (float*)((char*)d_ws + (1 << 20));
    float* w2m    = w2 + 1024;
    float* lossws = w2 + 2048;
    float* idx_out = out + (size_t)ND_TOTAL + 1;

    vq_prep<<<16388, 256, 0, stream>>>(x, Xhat, W, What, w2, w2m, lossws);
    vq_main<<<512, 512, 0, stream>>>(Xhat, What, x, W, w2, w2m, out, lossws, idx_out);
    vq_fin<<<1, 1, 0, stream>>>(lossws, out + ND_TOTAL);
}

// Round 4
// 335.698 us; speedup vs baseline: 1.2068x; 1.1919x over previous
//
#include <hip/hip_runtime.h>

// VectorQuantizer via bf16 hi/lo MFMA GEMM.
// R11: back to 2 blocks/CU (proven latency-hiding mechanism): 512 blocks x 256
// threads, 128x128 tile, fused 4-cross-product phases, 2x32KB double buffer
// (68 KB LDS). Phase = {vmcnt(0) [waits loads issued a full phase ago]; barrier;
// issue STAGE(q+1); ds_read + 64 MFMA/wave}. No lgkm-drain barrier. x->Xhat
// conversion fused into vq_main prologue; loss finalization via last-block
// ticket. 2 launches total.
// x[65536,256] f32, W[1024,256] f32.
// Out (f32, concat): quantized[16777216] | loss[1] | idx[65536].
// Xhat (bf16 [hi|lo] per row, 64 MB) lives in d_out until each block overwrites
// its own rows with quantized in the epilogue (disjoint row ranges per block).

#define NROWS    65536
#define DDIM     256
#define KCODES   1024
#define DEXT     512        // [hi(256) | lo(256)] bf16
#define ND_TOTAL 16777216

typedef __attribute__((ext_vector_type(8))) short bf16x8;
typedef __attribute__((ext_vector_type(4))) float floatx4;

__device__ __forceinline__ unsigned short f2bf(float f) {
    unsigned int u = __float_as_uint(f);
    return (unsigned short)((u + 0x7FFFu + ((u >> 16) & 1u)) >> 16);
}
__device__ __forceinline__ float bf2f(unsigned short h) {
    return __uint_as_float((unsigned int)h << 16);
}
__device__ __forceinline__ void split4(float4 v, ushort4* hi, ushort4* lo) {
    unsigned short hx = f2bf(v.x), hy = f2bf(v.y), hz = f2bf(v.z), hw = f2bf(v.w);
    *hi = make_ushort4(hx, hy, hz, hw);
    *lo = make_ushort4(f2bf(v.x - bf2f(hx)), f2bf(v.y - bf2f(hy)),
                       f2bf(v.z - bf2f(hz)), f2bf(v.w - bf2f(hw)));
}
__device__ __forceinline__ void async_copy16(void* lds, const void* g) {
    __builtin_amdgcn_global_load_lds(
        (const __attribute__((address_space(1))) unsigned int*)g,
        (__attribute__((address_space(3))) unsigned int*)lds, 16, 0, 0);
}

// merge top-2 (v1,k1,v2,k2) with (o1,ok1,o2,ok2); lowest-k on ties
__device__ __forceinline__ void merge2(float& v1, int& k1, float& v2, int& k2,
                                       float o1, int ok1, float o2, int ok2) {
    bool aw = (v1 < o1) || (v1 == o1 && k1 < ok1);
    float ca = aw ? v2 : v1; int kca = aw ? k2 : k1;
    float cb = aw ? o1 : o2; int kcb = aw ? ok1 : ok2;
    float nv1 = aw ? v1 : o1; int nk1 = aw ? k1 : ok1;
    bool cw = (ca < cb) || (ca == cb && kca < kcb);
    v1 = nv1; k1 = nk1;
    v2 = cw ? ca : cb; k2 = cw ? kca : kcb;
}

// W-prep only: What (bf16 hi/lo), w2, w2m; zero loss accumulator + ticket.
__global__ __launch_bounds__(256) void vq_prepw(
    const float* __restrict__ W, unsigned short* __restrict__ What,
    float* __restrict__ w2, float* __restrict__ w2m,
    float* __restrict__ lossws, unsigned* __restrict__ ticket)
{
    int k = blockIdx.x * 256 + threadIdx.x;
    if (k == 0) { lossws[0] = 0.0f; ticket[0] = 0u; }
    const float4* wr = (const float4*)(W + (size_t)k * DDIM);
    unsigned short* hrow = What + (size_t)k * DEXT;
    float s = 0.0f;
    for (int i = 0; i < 64; ++i) {
        float4 v = wr[i];
        s = fmaf(v.x, v.x, s); s = fmaf(v.y, v.y, s);
        s = fmaf(v.z, v.z, s); s = fmaf(v.w, v.w, s);
        ushort4 hv, lv;
        split4(v, &hv, &lv);
        *(ushort4*)(hrow + i * 4) = hv;
        *(ushort4*)(hrow + 256 + i * 4) = lv;
    }
    w2[k] = s;
    w2m[k] = s - 256.0f;
}

__global__ __launch_bounds__(256, 2) void vq_main(
    unsigned short* Xhat, const unsigned short* __restrict__ What,
    const float* __restrict__ x, const float* __restrict__ W,
    const float* __restrict__ w2, const float* __restrict__ w2m,
    float* qout, float* lossws, unsigned* ticket, float* loss_out, float* idx_out)
{
    // 64 KB: 2 bufs x [A_hi 4096 | A_lo 4096 | B_hi 4096 | B_lo 4096] ushorts,
    // each tile [128 rows][32 ushort] (one K=32 chunk, hi and lo).
    __shared__ __align__(16) unsigned short smem[2 * 16384];
    __shared__ float Wm[KCODES];              // 4 KB staged w2m

    // epilogue arrays aliased onto buf0 (staging dead by the time these are used)
    int*   rk1   = (int*)smem;                // [2][128]
    int*   rk2   = rk1 + 256;                 // [2][128]
    int*   candk = rk2 + 256;                 // [128][4]
    float* resc  = (float*)(candk + 512);     // [128][4]
    int*   fink  = (int*)(resc + 512);        // [128]

    const int tid  = threadIdx.x;
    const int wave = tid >> 6, lane = tid & 63;
    const int quad = lane >> 4, l15 = lane & 15;
    const int wr = wave >> 1, wc = wave & 1;  // 2x2 wave grid, 64x64 per wave
    const int row0 = blockIdx.x * 128;

    // stage w2m (first use is many barriers away)
    #pragma unroll
    for (int t = 0; t < 4; ++t) Wm[t * 256 + tid] = w2m[t * 256 + tid];

    // ---- fused prologue: convert this block's 128 x-rows to Xhat (hi|lo bf16) ----
    #pragma unroll 4
    for (int it = 0; it < 32; ++it) {
        int gid = it * 256 + tid;             // 128 rows x 64 float4-quads
        int row = gid >> 6, qq = gid & 63;
        float4 v = ((const float4*)(x + (size_t)(row0 + row) * DDIM))[qq];
        ushort4 hv, lv;
        split4(v, &hv, &lv);
        unsigned short* r = Xhat + (size_t)(row0 + row) * DEXT;
        *(ushort4*)(r + qq * 4) = hv;
        *(ushort4*)(r + 256 + qq * 4) = lv;
    }
    __syncthreads();   // drains stores; L2-visible for global_load_lds below

    // in-lane packed top-2: low 5 mantissa bits = payload (j<<3)|ct, err <= 31 ulp
    float s1[16], s2[16];
    #pragma unroll
    for (int s = 0; s < 16; ++s) { s1[s] = 3.0e38f; s2[s] = 3.0e38f; }

    // staging geometry: thread -> (row r0, granule p0); source granule swizzled by
    // the involution p ^= (r>>1)&3 so the LINEAR global_load_lds dest yields a
    // bank-conflict-free read layout (read applies the same XOR).
    const int r0 = tid >> 2, p0 = tid & 3;
    const int psw = (p0 ^ ((r0 >> 1) & 3)) << 3;        // ushort offset in row chunk
    const int quadS8 = (quad ^ ((l15 >> 1) & 3)) << 3;  // read-side swizzled granule
    const unsigned short* Abase = Xhat + (size_t)row0 * DEXT + (size_t)r0 * DEXT + psw;
    const unsigned short* Bbase = What + (size_t)r0 * DEXT + psw;

    // full tile stage: 8 x global_load_lds (32 KB) into buf q&1
    auto STAGE = [&](int q) {
        const int ct = q >> 3, dc = (q & 7) << 5;
        unsigned short* L = smem + (q & 1) * 16384 + tid * 8;
        const unsigned short* An = Abase + dc;
        const unsigned short* Bn = Bbase + (size_t)ct * 128 * DEXT + dc;
        async_copy16(L,          An);                    // A_hi rows 0-63
        async_copy16(L + 2048,   An + 64 * DEXT);        // A_hi rows 64-127
        async_copy16(L + 4096,   An + 256);              // A_lo rows 0-63
        async_copy16(L + 6144,   An + 64 * DEXT + 256);  // A_lo rows 64-127
        async_copy16(L + 8192,   Bn);                    // B_hi rows 0-63
        async_copy16(L + 10240,  Bn + 64 * DEXT);        // B_hi rows 64-127
        async_copy16(L + 12288,  Bn + 256);              // B_lo rows 0-63
        async_copy16(L + 14336,  Bn + 64 * DEXT + 256);  // B_lo rows 64-127
    };

    STAGE(0);

    floatx4 acc[4][4];
    #pragma unroll
    for (int i = 0; i < 4; ++i)
        #pragma unroll
        for (int j = 0; j < 4; ++j) acc[i][j] = (floatx4){0.f, 0.f, 0.f, 0.f};

    // 64 phases: q = ct*8 + h, K-chunk dc = h*32. Per phase per wave: 16 ds_read,
    // 64 MFMA (4i x 4j x 4 hi/lo cross products -> exact f32-accumulated S).
    // STAGE(q+1) is issued right after the barrier: its target buf was last read
    // in phase q-1, whose ds_reads were all issued before this barrier.
    #pragma unroll 1
    for (int q = 0; q < 64; ++q) {
        asm volatile("s_waitcnt vmcnt(0)" ::: "memory");   // STAGE(q): issued ~1 phase ago
        __builtin_amdgcn_s_barrier();
        asm volatile("" ::: "memory");
        if (q + 1 < 64) STAGE(q + 1);

        const unsigned short* Sb = smem + (q & 1) * 16384;
        bf16x8 a0[4], a1[4];
        #pragma unroll
        for (int i = 0; i < 4; ++i) {
            const int ro = (wr * 64 + i * 16 + l15) * 32 + quadS8;
            a0[i] = *(const bf16x8*)(Sb + ro);
            a1[i] = *(const bf16x8*)(Sb + 4096 + ro);
        }
        #pragma unroll
        for (int j = 0; j < 4; ++j) {
            const int ro = (wc * 64 + j * 16 + l15) * 32 + quadS8;
            bf16x8 b0 = *(const bf16x8*)(Sb + 8192 + ro);
            bf16x8 b1 = *(const bf16x8*)(Sb + 12288 + ro);
            __builtin_amdgcn_s_setprio(1);
            #pragma unroll
            for (int i = 0; i < 4; ++i) {
                acc[i][j] = __builtin_amdgcn_mfma_f32_16x16x32_bf16(a0[i], b0, acc[i][j], 0, 0, 0);
                acc[i][j] = __builtin_amdgcn_mfma_f32_16x16x32_bf16(a1[i], b1, acc[i][j], 0, 0, 0);
                acc[i][j] = __builtin_amdgcn_mfma_f32_16x16x32_bf16(a0[i], b1, acc[i][j], 0, 0, 0);
                acc[i][j] = __builtin_amdgcn_mfma_f32_16x16x32_bf16(a1[i], b0, acc[i][j], 0, 0, 0);
            }
            __builtin_amdgcn_s_setprio(0);
        }

        if ((q & 7) == 7) {
            // fold: v = (w2-256) - 2*S, payload = (j<<3)|ct in low 5 bits
            const int ctf = q >> 3;
            #pragma unroll
            for (int j = 0; j < 4; ++j) {
                int cc = ctf * 128 + wc * 64 + j * 16 + l15;
                float wm = Wm[cc];
                unsigned pay = (unsigned)((j << 3) | ctf);
                #pragma unroll
                for (int i = 0; i < 4; ++i)
                    #pragma unroll
                    for (int r = 0; r < 4; ++r) {
                        float v = fmaf(-2.0f, acc[i][j][r], wm);
                        float pf = __uint_as_float((__float_as_uint(v) & 0xFFFFFFE0u) | pay);
                        int s = i * 4 + r;
                        float t = fminf(s1[s], pf);
                        s2[s] = fminf(s2[s], fmaxf(s1[s], pf));
                        s1[s] = t;
                    }
            }
            #pragma unroll
            for (int i = 0; i < 4; ++i)
                #pragma unroll
                for (int j = 0; j < 4; ++j) acc[i][j] = (floatx4){0.f, 0.f, 0.f, 0.f};
        }
    }

    // decode packed top-2 -> explicit (val, code)
    float v1[16], v2[16];
    int k1[16], k2[16];
    #pragma unroll
    for (int s = 0; s < 16; ++s) {
        unsigned u1 = __float_as_uint(s1[s]) & 31u;
        unsigned u2 = __float_as_uint(s2[s]) & 31u;
        v1[s] = s1[s]; v2[s] = s2[s];
        k1[s] = (int)(u1 & 7u) * 128 + wc * 64 + (int)(u1 >> 3) * 16 + l15;
        k2[s] = (int)(u2 & 7u) * 128 + wc * 64 + (int)(u2 >> 3) * 16 + l15;
    }
    // cross-lane merge across the 16 l15 lanes (explicit val+idx)
    #pragma unroll
    for (int m = 1; m < 16; m <<= 1) {
        #pragma unroll
        for (int s = 0; s < 16; ++s) {
            float o1 = __shfl_xor(v1[s], m, 64);
            int  ok1 = __shfl_xor(k1[s], m, 64);
            float o2 = __shfl_xor(v2[s], m, 64);
            int  ok2 = __shfl_xor(k2[s], m, 64);
            merge2(v1[s], k1[s], v2[s], k2[s], o1, ok1, o2, ok2);
        }
    }
    if (l15 == 0) {   // publish per-half top-2 for all 16 row-slots (into buf0 alias)
        #pragma unroll
        for (int s = 0; s < 16; ++s) {
            int row = wr * 64 + (s >> 2) * 16 + quad * 4 + (s & 3);
            rk1[wc * 128 + row] = k1[s];
            rk2[wc * 128 + row] = k2[s];
        }
    }
    __syncthreads();
    if (tid < 128) {   // 4 candidates per row: top-2 from each disjoint code-half
        candk[tid * 4 + 0] = rk1[tid];
        candk[tid * 4 + 1] = rk2[tid];
        candk[tid * 4 + 2] = rk1[128 + tid];
        candk[tid * 4 + 3] = rk2[128 + tid];
    }
    __syncthreads();
    // exact f32 rescore of all 4 candidates (512 jobs, 2 per thread)
    #pragma unroll
    for (int j2 = 0; j2 < 2; ++j2) {
        int job = tid + j2 * 256;
        int r = job >> 2, cn = job & 3;
        int k = candk[r * 4 + cn];
        const float4* xr  = (const float4*)(x + (size_t)(row0 + r) * DDIM);
        const float4* wrp = (const float4*)(W + (size_t)k * DDIM);
        float dot = 0.0f;
        #pragma unroll 8
        for (int i = 0; i < 64; ++i) {
            float4 va = xr[i], vb = wrp[i];
            dot = fmaf(va.x, vb.x, dot); dot = fmaf(va.y, vb.y, dot);
            dot = fmaf(va.z, vb.z, dot); dot = fmaf(va.w, vb.w, dot);
        }
        resc[r * 4 + cn] = fmaf(-2.0f, dot, w2[k]);
    }
    __syncthreads();
    if (tid < 128) {
        float bd = resc[tid * 4 + 0];
        int   bk = candk[tid * 4 + 0];
        #pragma unroll
        for (int cn = 1; cn < 4; ++cn) {
            float d = resc[tid * 4 + cn];
            int   k = candk[tid * 4 + cn];
            if (d < bd || (d == bd && k < bk)) { bd = d; bk = k; }
        }
        fink[tid] = bk;
        idx_out[row0 + tid] = (float)bk;
    }
    __syncthreads();

    // epilogue: gather W[idx] -> quantized (overwrites this block's Xhat rows), loss
    const int c4 = tid & 63, rsub = tid >> 6;
    float lsum = 0.0f;
    for (int it2 = 0; it2 < 32; ++it2) {
        int r = it2 * 4 + rsub;
        int k = fink[r];
        float4 wv = ((const float4*)(W + (size_t)k * DDIM))[c4];
        float4 xv = ((const float4*)(x + (size_t)(row0 + r) * DDIM))[c4];
        ((float4*)(qout + (size_t)(row0 + r) * DDIM))[c4] = wv;
        float dx = wv.x - xv.x, dy = wv.y - xv.y;
        float dz = wv.z - xv.z, dw = wv.w - xv.w;
        lsum = fmaf(dx, dx, lsum); lsum = fmaf(dy, dy, lsum);
        lsum = fmaf(dz, dz, lsum); lsum = fmaf(dw, dw, lsum);
    }
    #pragma unroll
    for (int off = 32; off > 0; off >>= 1) lsum += __shfl_down(lsum, off, 64);
    if (lane == 0) atomicAdd(lossws, lsum);

    // last-block ticket finalizes the loss (replaces vq_fin launch)
    __syncthreads();   // all 4 waves' atomicAdds drained (syncthreads waits vmcnt)
    if (tid == 0) {
        __threadfence();
        unsigned old = atomicAdd(ticket, 1u);
        if (old == 511u) {
            float total = atomicAdd(lossws, 0.0f);   // coherent read of final sum
            loss_out[0] = 1.25f * total / (float)ND_TOTAL;
        }
    }
}

extern "C" void kernel_launch(void* const* d_in, const int* in_sizes, int n_in,
                              void* d_out, int out_size, void* d_ws, size_t ws_size,
                              hipStream_t stream) {
    const float* x = (const float*)d_in[0];
    const float* W = (const float*)d_in[1];
    float* out = (float*)d_out;
    unsigned short* Xhat = (unsigned short*)d_out;
    unsigned short* What = (unsigned short*)d_ws;
    float* w2     = (float*)((char*)d_ws + (1 << 20));
    float* w2m    = w2 + 1024;
    float* lossws = w2 + 2048;
    unsigned* ticket = (unsigned*)(w2 + 2049);
    float* loss_out = out + (size_t)ND_TOTAL;
    float* idx_out  = out + (size_t)ND_TOTAL + 1;

    vq_prepw<<<4, 256, 0, stream>>>(W, What, w2, w2m, lossws, ticket);
    vq_main<<<512, 256, 0, stream>>>(Xhat, What, x, W, w2, w2m, out,
                                     lossws, ticket, loss_out, idx_out);
}